// Round 14
// baseline (156.992 us; speedup 1.0000x reference)
//
#include <hip/hip_runtime.h>

// raw barrier: wait LDS ops only (NOT vmcnt) so global loads/stores stay in
// flight across the barrier. "memory" clobber pins C++ LDS access order.
#define BAR() do { asm volatile("s_waitcnt lgkmcnt(0)" ::: "memory"); \
                   __builtin_amdgcn_s_barrier();                      \
                   asm volatile("" ::: "memory"); } while (0)

// -------- radix-8 inverse DFT over register index: u[n] = sum_k v[k] e^{+2*pi*i*n*k/8}
__device__ __forceinline__ void dft8(float* vr, float* vi) {
    float t0r=vr[0]+vr[4], t0i=vi[0]+vi[4];
    float t1r=vr[0]-vr[4], t1i=vi[0]-vi[4];
    float t2r=vr[2]+vr[6], t2i=vi[2]+vi[6];
    float t3r=vr[2]-vr[6], t3i=vi[2]-vi[6];
    float t4r=vr[1]+vr[5], t4i=vi[1]+vi[5];
    float t5r=vr[1]-vr[5], t5i=vi[1]-vi[5];
    float t6r=vr[3]+vr[7], t6i=vi[3]+vi[7];
    float t7r=vr[3]-vr[7], t7i=vi[3]-vi[7];
    float e0r=t0r+t2r, e0i=t0i+t2i;
    float e1r=t1r-t3i, e1i=t1i+t3r;   // t1 + i*t3
    float e2r=t0r-t2r, e2i=t0i-t2i;
    float e3r=t1r+t3i, e3i=t1i-t3r;   // t1 - i*t3
    float o0r=t4r+t6r, o0i=t4i+t6i;
    float o1r=t5r-t7i, o1i=t5i+t7r;
    float o2r=t4r-t6r, o2i=t4i-t6i;
    float o3r=t5r+t7i, o3i=t5i-t7r;
    const float C = 0.70710678118654752f;
    float w1r = C*(o1r - o1i), w1i = C*(o1r + o1i);   // W8^1 * o1
    float w2r = -o2i,          w2i = o2r;             // i * o2
    float w3r = -C*(o3r + o3i), w3i = C*(o3r - o3i);  // W8^3 * o3
    vr[0]=e0r+o0r; vi[0]=e0i+o0i;
    vr[1]=e1r+w1r; vi[1]=e1i+w1i;
    vr[2]=e2r+w2r; vi[2]=e2i+w2i;
    vr[3]=e3r+w3r; vi[3]=e3i+w3i;
    vr[4]=e0r-o0r; vi[4]=e0i-o0i;
    vr[5]=e1r-w1r; vi[5]=e1i-w1i;
    vr[6]=e2r-w2r; vi[6]=e2i-w2i;
    vr[7]=e3r-w3r; vi[7]=e3i-w3i;
}

// packed irfft-1024 as 512-pt complex IFFT, in-place in split re/im slot
__device__ __forceinline__ void fft512(float* Re, float* Im, int l,
                                       const float2* s_twzb, const float2* s_tw64,
                                       const float2* s_tw512) {
    const int a_ = l >> 3, b_ = l & 7;
    float zr[8], zi[8];
    float cw = s_twzb[l].x, sw_ = s_twzb[l].y;
    const float C8 = 0.92387953251128675f, S8 = 0.38268343236508977f; // e^{i*pi/8}
    #pragma unroll
    for (int k0 = 0; k0 < 8; ++k0) {
        int k = (k0<<6) + l;
        float xkr = Re[k],     xki = Im[k];
        float xmr = Re[512-k], xmi = Im[512-k];
        if (k == 0) { xki = 0.f; xmi = 0.f; }   // zero Im(X0), Im(X512)
        float Er = 0.5f*(xkr + xmr), Ei = 0.5f*(xki - xmi);
        float Dr = 0.5f*(xkr - xmr), Di = 0.5f*(xki + xmi);
        float Or = cw*Dr - sw_*Di,  Oi = sw_*Dr + cw*Di;
        zr[k0] = Er - Oi;
        zi[k0] = Ei + Or;
        float nc = cw*C8 - sw_*S8; sw_ = sw_*C8 + cw*S8; cw = nc;
    }
    dft8(zr, zi);
    // exchange 1 (XOR-swizzled, <=2-way)
    #pragma unroll
    for (int q = 0; q < 8; ++q) {
        int idx = (q<<6) + l;
        Re[idx ^ (((idx>>6)&7)<<3)] = zr[q];
        Im[idx ^ (((idx>>6)&7)<<3)] = zi[q];
    }
    #pragma unroll
    for (int q = 0; q < 8; ++q) {
        int idx = (a_<<6) + (q<<3) + b_;
        int ph = idx ^ (((idx>>6)&7)<<3);
        zr[q] = Re[ph]; zi[q] = Im[ph];
    }
    { // twiddle2: w64^{n0*k1}, incremental
        float c1 = s_tw64[a_].x, s1 = s_tw64[a_].y;
        float cr = c1, ci = s1;
        #pragma unroll
        for (int q = 1; q < 8; ++q) {
            float tr = zr[q]*cr - zi[q]*ci;
            zi[q] = zr[q]*ci + zi[q]*cr;
            zr[q] = tr;
            float nc = cr*c1 - ci*s1; ci = ci*c1 + cr*s1; cr = nc;
        }
    }
    dft8(zr, zi);
    // exchange 2
    #pragma unroll
    for (int q = 0; q < 8; ++q) {
        int idx = (b_<<6) + (q<<3) + a_;
        int ph = idx ^ (((idx>>6)&7)<<3);
        Re[ph] = zr[q]; Im[ph] = zi[q];
    }
    #pragma unroll
    for (int q = 0; q < 8; ++q) {
        int idx = (q<<6) + l;
        int ph = idx ^ (((idx>>6)&7)<<3);
        zr[q] = Re[ph]; zi[q] = Im[ph];
    }
    { // twiddle3: w512^{(n1*8+n0)*k2}, incremental
        float c1 = s_tw512[l].x, s1 = s_tw512[l].y;
        float cr = c1, ci = s1;
        #pragma unroll
        for (int q = 1; q < 8; ++q) {
            float tr = zr[q]*cr - zi[q]*ci;
            zi[q] = zr[q]*ci + zi[q]*cr;
            zr[q] = tr;
            float nc = cr*c1 - ci*s1; ci = ci*c1 + cr*s1; cr = nc;
        }
    }
    dft8(zr, zi);
    // output: lane l, reg q holds z[64q + l]; x[2n]=Re z[n], x[2n+1]=Im z[n]
    #pragma unroll
    for (int q = 0; q < 8; ++q) {
        Re[(q<<6) + l] = zr[q];
        Im[(q<<6) + l] = zi[q];
    }
}

// one block = (batch b, 64 frames as 4 pipelined 16-frame tiles).
// Tile t+1's global loads issue after tile t's FFT barrier -> HBM latency
// hides under gather(t)+stage(t+1). Internal seams carried in registers
// (no ws/atomics) -> only block-boundary seams (G%4==0) need fixup.
template<bool USE_WS>
__global__ __launch_bounds__(1024, 8) void istft_main(const float* __restrict__ spec_re,
                                                      const float* __restrict__ spec_im,
                                                      const float* __restrict__ mask,
                                                      float* __restrict__ out,
                                                      float* __restrict__ wsL,
                                                      float* __restrict__ wsR)
{
    const int g2  = blockIdx.x;   // 0..31: tiles G = 4*g2 .. 4*g2+3
    const int b   = blockIdx.y;   // batch 0..15
    const int tid = threadIdx.x;

    __shared__ __attribute__((aligned(16))) float s_slot[16704]; // 16 slots x 522 x {re,im}
    __shared__ __attribute__((aligned(16))) float s_wt[1024];    // hann(j)/512
    __shared__ __attribute__((aligned(16))) float s_envr[256];   // 1/fold(hann^2)
    __shared__ float  s_maskx[22];    // mask frames 16G-3 .. 16G+18 (OOR = 0)
    __shared__ float  s_ps[23];       // prefix sums of s_maskx
    __shared__ float2 s_twzb[64];     // e^{i*pi*l/512}
    __shared__ float2 s_tw64[8];      // e^{2*pi*i*a/64}
    __shared__ float2 s_tw512[64];    // e^{2*pi*i*l/512}

    const int c  = tid & 3;
    const int r0 = tid >> 2;          // 0..255
    float4 vr0, vi0, vr1, vi1, nyr, nyi, mk;
    float  mxv = 0.f;

#define ISSUE_LOADS(GG) do {                                                     \
        size_t base_ = (size_t)b * 513 * 2048 + (size_t)((GG) * 16);             \
        size_t o0_ = base_ + (size_t)(r0      ) * 2048 + (size_t)(c * 4);        \
        size_t o1_ = base_ + (size_t)(r0 + 256) * 2048 + (size_t)(c * 4);        \
        vr0 = *(const float4*)(spec_re + o0_);  vi0 = *(const float4*)(spec_im + o0_); \
        vr1 = *(const float4*)(spec_re + o1_);  vi1 = *(const float4*)(spec_im + o1_); \
        if (tid < 4) {                                                           \
            size_t o2_ = base_ + (size_t)512 * 2048 + (size_t)(tid * 4);         \
            nyr = *(const float4*)(spec_re + o2_);                               \
            nyi = *(const float4*)(spec_im + o2_);                               \
        }                                                                        \
        mk = *(const float4*)(mask + b*2048 + (GG)*16 + c*4);                    \
        if (tid < 22) {                                                          \
            int gf_ = (GG)*16 - 3 + tid;                                         \
            mxv = (gf_ >= 0 && gf_ < 2048) ? mask[b*2048 + gf_] : 0.f;           \
        }                                                                        \
    } while (0)

    // ---- prologue: issue tile-0 loads, then build tables under the latency ----
    const int G0 = g2 << 2;
    ISSUE_LOADS(G0);
    {
        float w = 0.5f - 0.5f * __cosf(6.2831853071795864f * (float)tid * (1.0f/1024.0f));
        s_wt[tid] = w * (1.0f/512.0f);
    }
    if (tid < 256) {
        float e = 0.f;
        #pragma unroll
        for (int k = 0; k < 4; ++k) {
            float w = 0.5f - 0.5f * __cosf(6.2831853071795864f * (float)(tid + (k<<8)) * (1.0f/1024.0f));
            e += w * w;
        }
        s_envr[tid] = 1.0f / e;
    }
    if (tid < 64) {
        float s1, c1, s2, c2;
        __sincosf(3.1415926535897932f * (float)tid * (1.0f/512.0f), &s1, &c1);
        s_twzb[tid] = make_float2(c1, s1);
        __sincosf(6.2831853071795864f * (float)tid * (1.0f/512.0f), &s2, &c2);
        s_tw512[tid] = make_float2(c2, s2);
    }
    if (tid < 8) {
        float s3, c3;
        __sincosf(6.2831853071795864f * (float)tid * (1.0f/64.0f), &s3, &c3);
        s_tw64[tid] = make_float2(c3, s3);
    }

    float* yout = out + (size_t)b * 524288;
    float* mout = out + 16ull*524288 + (size_t)b * 524288;
    float4 carry = {0.f, 0.f, 0.f, 0.f};    // right-strip partials of prev tile

    for (int t = 0; t < 4; ++t) {
        const int G  = G0 + t;
        const int P0 = G << 12;

        // ---- stage this tile (regs -> LDS, mask folded) ----
        if (tid < 22) s_maskx[tid] = mxv;
        {
            const float* mp = (const float*)&mk;
            #pragma unroll
            for (int f = 0; f < 4; ++f) {
                int fr = (c*4 + f) * 522;
                s_slot[       fr + r0      ] = ((const float*)&vr0)[f] * mp[f];
                s_slot[8352 + fr + r0      ] = ((const float*)&vi0)[f] * mp[f];
                s_slot[       fr + r0 + 256] = ((const float*)&vr1)[f] * mp[f];
                s_slot[8352 + fr + r0 + 256] = ((const float*)&vi1)[f] * mp[f];
            }
            if (tid < 4) {
                #pragma unroll
                for (int f = 0; f < 4; ++f) {
                    int fr = (tid*4 + f) * 522;
                    s_slot[       fr + 512] = ((const float*)&nyr)[f] * mp[f];
                    s_slot[8352 + fr + 512] = ((const float*)&nyi)[f] * mp[f];
                }
            }
        }
        if (tid == 0) {
            float acc = 0.f;
            s_ps[0] = 0.f;
            #pragma unroll
            for (int i = 0; i < 22; ++i) { acc += s_maskx[i]; s_ps[i+1] = acc; }
        }
        BAR();   // staging + s_ps (+ tables on t=0) visible

        // ---- FFT: wave wv (0..15) handles frame wv ----
        __builtin_amdgcn_s_setprio(1);
        {
            const int wv = tid >> 6, l = tid & 63;
            fft512(&s_slot[wv*522], &s_slot[8352 + wv*522], l, s_twzb, s_tw64, s_tw512);
        }
        __builtin_amdgcn_s_setprio(0);
        BAR();   // FFT results visible

        // ---- issue next tile's loads (hidden under gather; short live range) ----
        if (t < 3) ISSUE_LOADS(G + 1);

        // ---- quad gather + retire ----
        {
            const int p0 = tid << 2;
            if (p0 >= 768) {
                // interior: exactly 4 frames
                const int F0 = (p0 >> 8) - 3;
                float4 acc = {0.f, 0.f, 0.f, 0.f};
                #pragma unroll
                for (int u = 0; u < 4; ++u) {
                    int F = F0 + u;
                    int j = p0 - (F << 8);
                    float2 re = *(const float2*)&s_slot[       F*522 + (j >> 1)];
                    float2 im = *(const float2*)&s_slot[8352 + F*522 + (j >> 1)];
                    float4 w4 = *(const float4*)&s_wt[j];
                    acc.x += re.x * w4.x;  acc.y += im.x * w4.y;
                    acc.z += re.y * w4.z;  acc.w += im.y * w4.w;
                }
                float fm = s_ps[(p0 >> 8) + 4] - s_ps[F0 + 3];
                float m = (fm > 0.f) ? 1.0f : 0.0f;
                float4 er = *(const float4*)&s_envr[p0 & 255];
                int s = P0 + p0 - 384;
                float4 r;
                r.x = acc.x * er.x;  r.y = acc.y * er.y;
                r.z = acc.z * er.z;  r.w = acc.w * er.w;
                *(float4*)&yout[s] = r;
                float4 mm = {m, m, m, m};
                *(float4*)&mout[s] = mm;
            } else {
                // left strip quad (seam with tile t-1 / block G-1)
                const int thi = p0 >> 8;          // 0..2
                float4 acc = {0.f, 0.f, 0.f, 0.f};
                for (int F = 0; F <= thi; ++F) {
                    int j = p0 - (F << 8);
                    float2 re = *(const float2*)&s_slot[       F*522 + (j >> 1)];
                    float2 im = *(const float2*)&s_slot[8352 + F*522 + (j >> 1)];
                    float4 w4 = *(const float4*)&s_wt[j];
                    acc.x += re.x * w4.x;  acc.y += im.x * w4.y;
                    acc.z += re.y * w4.z;  acc.w += im.y * w4.w;
                }
                float fm = s_ps[thi + 4] - s_ps[((p0 - 768) >> 8) + 3];
                float m = (fm > 0.f) ? 1.0f : 0.0f;
                float4 mm = {m, m, m, m};
                if (t > 0) {
                    // internal seam: combine with carried partials, final write
                    acc.x += carry.x;  acc.y += carry.y;
                    acc.z += carry.z;  acc.w += carry.w;
                    float4 er = *(const float4*)&s_envr[p0 & 255];
                    int s = P0 + p0 - 384;
                    float4 r;
                    r.x = acc.x * er.x;  r.y = acc.y * er.y;
                    r.z = acc.z * er.z;  r.w = acc.w * er.w;
                    *(float4*)&yout[s] = r;
                    *(float4*)&mout[s] = mm;
                } else if (G == 0) {
                    if (p0 >= 384) {
                        float4 e = {0.f, 0.f, 0.f, 0.f};
                        for (int tt = 0; tt <= thi; ++tt) {
                            float4 w4 = *(const float4*)&s_wt[p0 - (tt << 8)];
                            e.x += w4.x * w4.x;  e.y += w4.y * w4.y;
                            e.z += w4.z * w4.z;  e.w += w4.w * w4.w;
                        }
                        const float S = 1.0f / 262144.0f;   // e_true = e * 512^2
                        float4 r;
                        r.x = acc.x * S / e.x;  r.y = acc.y * S / e.y;
                        r.z = acc.z * S / e.z;  r.w = acc.w * S / e.w;
                        *(float4*)&yout[p0 - 384] = r;
                        *(float4*)&mout[p0 - 384] = mm;
                    }
                } else {
                    // block-boundary seam: stash partials
                    int s = P0 + p0 - 384;
                    if (USE_WS) {
                        *(float4*)&wsL[(size_t)((b << 7) + G) * 768 + p0] = acc;
                    } else {
                        atomicAdd(&yout[s+0], acc.x);  atomicAdd(&yout[s+1], acc.y);
                        atomicAdd(&yout[s+2], acc.z);  atomicAdd(&yout[s+3], acc.w);
                    }
                    *(float4*)&mout[s] = mm;
                }
            }
        }
        // right strip quad p0 = 4096 + 4*tid (tid < 192)
        if (tid < 192) {
            const int p0 = 4096 + (tid << 2);
            const int Flo = (p0 - 768) >> 8;       // 13..15
            float4 acc = {0.f, 0.f, 0.f, 0.f};
            for (int F = Flo; F < 16; ++F) {
                int j = p0 - (F << 8);
                float2 re = *(const float2*)&s_slot[       F*522 + (j >> 1)];
                float2 im = *(const float2*)&s_slot[8352 + F*522 + (j >> 1)];
                float4 w4 = *(const float4*)&s_wt[j];
                acc.x += re.x * w4.x;  acc.y += im.x * w4.y;
                acc.z += re.y * w4.z;  acc.w += im.y * w4.w;
            }
            if (t < 3) {
                carry = acc;                        // consumed by next tile's left strip
            } else if (G == 127) {
                if (p0 < 4480) {
                    float fm = s_ps[min(p0 >> 8, 18) + 4] - s_ps[Flo + 3];
                    float m = (fm > 0.f) ? 1.0f : 0.0f;
                    float4 mm = {m, m, m, m};
                    float4 e = {0.f, 0.f, 0.f, 0.f};
                    for (int tt = Flo; tt < 16; ++tt) {
                        float4 w4 = *(const float4*)&s_wt[p0 - (tt << 8)];
                        e.x += w4.x * w4.x;  e.y += w4.y * w4.y;
                        e.z += w4.z * w4.z;  e.w += w4.w * w4.w;
                    }
                    const float S = 1.0f / 262144.0f;
                    int s = P0 + p0 - 384;
                    float4 r;
                    r.x = acc.x * S / e.x;  r.y = acc.y * S / e.y;
                    r.z = acc.z * S / e.z;  r.w = acc.w * S / e.w;
                    *(float4*)&yout[s] = r;
                    *(float4*)&mout[s] = mm;
                }
            } else {
                // block-boundary seam: stash partials
                float fm = s_ps[min(p0 >> 8, 18) + 4] - s_ps[Flo + 3];
                float m = (fm > 0.f) ? 1.0f : 0.0f;
                float4 mm = {m, m, m, m};
                int s = P0 + p0 - 384;
                if (USE_WS) {
                    *(float4*)&wsR[(size_t)((b << 7) + G) * 768 + (p0 - 4096)] = acc;
                } else {
                    atomicAdd(&yout[s+0], acc.x);  atomicAdd(&yout[s+1], acc.y);
                    atomicAdd(&yout[s+2], acc.z);  atomicAdd(&yout[s+3], acc.w);
                }
                *(float4*)&mout[s] = mm;
            }
        }
        if (t < 3) BAR();   // all gather reads done -> slots free for next stage
    }
#undef ISSUE_LOADS
}

// ws path: combine the two strip partials at block-boundary seams (G = 4,8,..,124).
__global__ void istft_fixup_ws(const float* __restrict__ wsL, const float* __restrict__ wsR,
                               float* __restrict__ out) {
    int idx = blockIdx.x * 256 + threadIdx.x;   // quad index
    if (idx >= 16*31*192) return;
    int q4 = (idx % 192) << 2;        // 0..764
    int t_ = idx / 192;
    int g  = ((t_ % 31) + 1) << 2;    // 4..124
    int b  = t_ / 31;
    float4 aR = *(const float4*)&wsR[(size_t)((b << 7) + (g-1)) * 768 + q4];
    float4 aL = *(const float4*)&wsL[(size_t)((b << 7) + g) * 768 + q4];
    float4 r;
    #pragma unroll
    for (int cmp = 0; cmp < 4; ++cmp) {
        int j0 = (q4 + cmp) & 255;
        float e = 0.f;
        #pragma unroll
        for (int u = 0; u < 4; ++u) {
            float w = 0.5f - 0.5f * __cosf(6.2831853071795864f * (float)(j0 + (u<<8)) * (1.0f/1024.0f));
            e += w * w;
        }
        float a = ((const float*)&aR)[cmp] + ((const float*)&aL)[cmp];
        ((float*)&r)[cmp] = a / e;
    }
    *(float4*)&out[(size_t)b*524288 + (size_t)((g << 12) + q4 - 384)] = r;
}

// atomic-fallback path (block-boundary strips only)
__global__ void istft_zero(float* __restrict__ out) {
    int idx = blockIdx.x * 256 + threadIdx.x;
    if (idx >= 16*31*768) return;
    int q  = idx % 768;
    int t_ = idx / 768;
    int g  = ((t_ % 31) + 1) << 2;
    int b  = t_ / 31;
    out[(size_t)b*524288 + (g << 12) + q - 384] = 0.f;
}

__global__ void istft_fixup_at(float* __restrict__ out) {
    int idx = blockIdx.x * 256 + threadIdx.x;
    if (idx >= 16*31*768) return;
    int q  = idx % 768;
    int t_ = idx / 768;
    int g  = ((t_ % 31) + 1) << 2;
    int b  = t_ / 31;
    int j0 = q & 255;
    float e = 0.f;
    #pragma unroll
    for (int u = 0; u < 4; ++u) {
        float w = 0.5f - 0.5f * __cosf(6.2831853071795864f * (float)(j0 + (u<<8)) * (1.0f/1024.0f));
        e += w * w;
    }
    size_t o = (size_t)b*524288 + (size_t)((g << 12) + q - 384);
    out[o] = out[o] / e;
}

extern "C" void kernel_launch(void* const* d_in, const int* in_sizes, int n_in,
                              void* d_out, int out_size, void* d_ws, size_t ws_size,
                              hipStream_t stream) {
    (void)in_sizes; (void)n_in; (void)out_size;
    const float* spec_re = (const float*)d_in[0];
    const float* spec_im = (const float*)d_in[1];
    const float* mask    = (const float*)d_in[2];
    float* out = (float*)d_out;
    const size_t ws_need = 2ull * 16 * 128 * 768 * 4;   // 12.6 MB
    if (ws_size >= ws_need && d_ws != nullptr) {
        float* wsL = (float*)d_ws;
        float* wsR = wsL + 16ull*128*768;
        istft_main<true><<<dim3(32, 16), 1024, 0, stream>>>(spec_re, spec_im, mask, out, wsL, wsR);
        const int nq = 16*31*192;
        istft_fixup_ws<<<(nq + 255)/256, 256, 0, stream>>>(wsL, wsR, out);
    } else {
        const int nstrip = 16*31*768;
        istft_zero<<<(nstrip + 255)/256, 256, 0, stream>>>(out);
        istft_main<false><<<dim3(32, 16), 1024, 0, stream>>>(spec_re, spec_im, mask, out, nullptr, nullptr);
        istft_fixup_at<<<(nstrip + 255)/256, 256, 0, stream>>>(out);
    }
}

// Round 15
// 81.935 us; speedup vs baseline: 1.9161x; 1.9161x over previous
//
#include <hip/hip_runtime.h>

#define THREADS 1024
#define CSTRIDE 514   // complex (float2) units per slot: 513 used + pad

// raw barrier: wait LDS ops only (NOT vmcnt) so global loads/stores stay in
// flight across the barrier. "memory" clobber pins C++ LDS access order.
#define BAR() do { asm volatile("s_waitcnt lgkmcnt(0)" ::: "memory"); \
                   __builtin_amdgcn_s_barrier();                      \
                   asm volatile("" ::: "memory"); } while (0)

// XOR swizzle on the COMPLEX index; bijective within 64-blocks, fixes 512.
__device__ __forceinline__ int swz(int i) { return i ^ (((i >> 6) & 7) << 3); }

// -------- radix-8 inverse DFT over register index: u[n] = sum_k v[k] e^{+2*pi*i*n*k/8}
__device__ __forceinline__ void dft8(float* vr, float* vi) {
    float t0r=vr[0]+vr[4], t0i=vi[0]+vi[4];
    float t1r=vr[0]-vr[4], t1i=vi[0]-vi[4];
    float t2r=vr[2]+vr[6], t2i=vi[2]+vi[6];
    float t3r=vr[2]-vr[6], t3i=vi[2]-vi[6];
    float t4r=vr[1]+vr[5], t4i=vi[1]+vi[5];
    float t5r=vr[1]-vr[5], t5i=vi[1]-vi[5];
    float t6r=vr[3]+vr[7], t6i=vi[3]+vi[7];
    float t7r=vr[3]-vr[7], t7i=vi[3]-vi[7];
    float e0r=t0r+t2r, e0i=t0i+t2i;
    float e1r=t1r-t3i, e1i=t1i+t3r;   // t1 + i*t3
    float e2r=t0r-t2r, e2i=t0i-t2i;
    float e3r=t1r+t3i, e3i=t1i-t3r;   // t1 - i*t3
    float o0r=t4r+t6r, o0i=t4i+t6i;
    float o1r=t5r-t7i, o1i=t5i+t7r;
    float o2r=t4r-t6r, o2i=t4i-t6i;
    float o3r=t5r+t7i, o3i=t5i-t7r;
    const float C = 0.70710678118654752f;
    float w1r = C*(o1r - o1i), w1i = C*(o1r + o1i);   // W8^1 * o1
    float w2r = -o2i,          w2i = o2r;             // i * o2
    float w3r = -C*(o3r + o3i), w3i = C*(o3r - o3i);  // W8^3 * o3
    vr[0]=e0r+o0r; vi[0]=e0i+o0i;
    vr[1]=e1r+w1r; vi[1]=e1i+w1i;
    vr[2]=e2r+w2r; vi[2]=e2i+w2i;
    vr[3]=e3r+w3r; vi[3]=e3i+w3i;
    vr[4]=e0r-o0r; vi[4]=e0i-o0i;
    vr[5]=e1r-w1r; vi[5]=e1i-w1i;
    vr[6]=e2r-w2r; vi[6]=e2i-w2i;
    vr[7]=e3r-w3r; vi[7]=e3i-w3i;
}

// packed irfft-1024 as 512-pt complex IFFT, in-place, interleaved-complex slot.
// Incremental twiddle chains (R12-proven) — NO per-q table lookups (R13's
// tw512f[(l*q)&511] was an 8..32-way bank conflict at q=8,16,32).
__device__ __forceinline__ void fft512i(float2* S, int l,
                                        const float2* s_twzb, const float2* s_tw64,
                                        const float2* s_tw512) {
    const int a_ = l >> 3, b_ = l & 7;
    float zr[8], zi[8];
    float cw = s_twzb[l].x, sw_ = s_twzb[l].y;
    const float C8 = 0.92387953251128675f, S8 = 0.38268343236508977f; // e^{i*pi/8}
    #pragma unroll
    for (int k0 = 0; k0 < 8; ++k0) {
        int k = (k0<<6) + l;
        float2 xk = S[swz(k)];
        float2 xm = S[swz(512-k)];
        if (k == 0) { xk.y = 0.f; xm.y = 0.f; }   // zero Im(X0), Im(X512)
        float Er = 0.5f*(xk.x + xm.x), Ei = 0.5f*(xk.y - xm.y);
        float Dr = 0.5f*(xk.x - xm.x), Di = 0.5f*(xk.y + xm.y);
        float Or = cw*Dr - sw_*Di,  Oi = sw_*Dr + cw*Di;
        zr[k0] = Er - Oi;
        zi[k0] = Ei + Or;
        float nc = cw*C8 - sw_*S8; sw_ = sw_*C8 + cw*S8; cw = nc;
    }
    dft8(zr, zi);
    // exchange 1
    #pragma unroll
    for (int q = 0; q < 8; ++q)
        S[swz((q<<6) + l)] = make_float2(zr[q], zi[q]);
    #pragma unroll
    for (int q = 0; q < 8; ++q) {
        float2 t = S[swz((a_<<6) + (q<<3) + b_)];
        zr[q] = t.x; zi[q] = t.y;
    }
    { // twiddle2: w64^{a_*q}, incremental chain (s_tw64[a_] is 8-lane broadcast)
        float c1 = s_tw64[a_].x, s1 = s_tw64[a_].y;
        float cr = c1, ci = s1;
        #pragma unroll
        for (int q = 1; q < 8; ++q) {
            float tr = zr[q]*cr - zi[q]*ci;
            zi[q] = zr[q]*ci + zi[q]*cr;
            zr[q] = tr;
            float nc = cr*c1 - ci*s1; ci = ci*c1 + cr*s1; cr = nc;
        }
    }
    dft8(zr, zi);
    // exchange 2
    #pragma unroll
    for (int q = 0; q < 8; ++q)
        S[swz((b_<<6) + (q<<3) + a_)] = make_float2(zr[q], zi[q]);
    #pragma unroll
    for (int q = 0; q < 8; ++q) {
        float2 t = S[swz((q<<6) + l)];
        zr[q] = t.x; zi[q] = t.y;
    }
    { // twiddle3: w512^{l*q}, incremental chain (s_tw512[l] is bank-floor)
        float c1 = s_tw512[l].x, s1 = s_tw512[l].y;
        float cr = c1, ci = s1;
        #pragma unroll
        for (int q = 1; q < 8; ++q) {
            float tr = zr[q]*cr - zi[q]*ci;
            zi[q] = zr[q]*ci + zi[q]*cr;
            zr[q] = tr;
            float nc = cr*c1 - ci*s1; ci = ci*c1 + cr*s1; cr = nc;
        }
    }
    dft8(zr, zi);
    // output: complex elem n=64q+l holds (x[2n], x[2n+1]) at swizzled slot
    #pragma unroll
    for (int q = 0; q < 8; ++q)
        S[swz((q<<6) + l)] = make_float2(zr[q], zi[q]);
}

// one block = (batch b, 16 frames), 16 interleaved-complex LDS slots,
// 1024 threads = 16 waves, one fft512 per wave, quad-b128 gather.
template<bool USE_WS>
__global__ __launch_bounds__(1024, 8) void istft_main(const float* __restrict__ spec_re,
                                                      const float* __restrict__ spec_im,
                                                      const float* __restrict__ mask,
                                                      float* __restrict__ out,
                                                      float* __restrict__ wsL,
                                                      float* __restrict__ wsR)
{
    const int G   = blockIdx.x;   // frame-group 0..127 (frames [16G, 16G+16))
    const int b   = blockIdx.y;   // batch 0..15
    const int tid = threadIdx.x;

    __shared__ __attribute__((aligned(16))) float2 s_slot[16*CSTRIDE];
    __shared__ __attribute__((aligned(16))) float  s_wt[1024];    // hann(j)/512
    __shared__ __attribute__((aligned(16))) float  s_envr[256];   // 1/fold(hann^2)
    __shared__ float  s_maskx[22];    // mask frames 16G-3 .. 16G+18 (OOR = 0)
    __shared__ float  s_ps[23];       // prefix sums of s_maskx
    __shared__ float2 s_twzb[64];     // e^{i*pi*l/512}
    __shared__ float2 s_tw64[8];      // e^{2*pi*i*a/64}
    __shared__ float2 s_tw512[64];    // e^{2*pi*i*l/512}

    // ---- issue ALL global loads FIRST (latency hides under table build) ----
    const size_t base = (size_t)b * 513 * 2048 + (size_t)(G * 16);
    const int c  = tid & 3;
    const int r0 = tid >> 2;          // 0..255
    float4 vr0, vi0, vr1, vi1, nyr, nyi;
    float4 mk;
    float mxv = 0.f;
    {
        size_t o0 = base + (size_t)(r0      ) * 2048 + (size_t)(c * 4);
        size_t o1 = base + (size_t)(r0 + 256) * 2048 + (size_t)(c * 4);
        vr0 = *(const float4*)(spec_re + o0);  vi0 = *(const float4*)(spec_im + o0);
        vr1 = *(const float4*)(spec_re + o1);  vi1 = *(const float4*)(spec_im + o1);
        if (tid < 4) {   // Nyquist row 512, chunk tid
            size_t o2 = base + (size_t)512 * 2048 + (size_t)(tid * 4);
            nyr = *(const float4*)(spec_re + o2);
            nyi = *(const float4*)(spec_im + o2);
        }
        mk = *(const float4*)(mask + b*2048 + G*16 + c*4);
        if (tid < 22) {
            int gf = G*16 - 3 + tid;
            mxv = (gf >= 0 && gf < 2048) ? mask[b*2048 + gf] : 0.f;
        }
    }

    // ---- tables (hardware trig; accuracy ~1e-5 << 2e-2 threshold) ----
    {
        float w = 0.5f - 0.5f * __cosf(6.2831853071795864f * (float)tid * (1.0f/1024.0f));
        s_wt[tid] = w * (1.0f/512.0f);
    }
    if (tid < 256) {
        float e = 0.f;
        #pragma unroll
        for (int k = 0; k < 4; ++k) {
            float w = 0.5f - 0.5f * __cosf(6.2831853071795864f * (float)(tid + (k<<8)) * (1.0f/1024.0f));
            e += w * w;
        }
        s_envr[tid] = 1.0f / e;
    }
    if (tid < 64) {
        float s1, c1, s2, c2;
        __sincosf(3.1415926535897932f * (float)tid * (1.0f/512.0f), &s1, &c1);
        s_twzb[tid] = make_float2(c1, s1);
        __sincosf(6.2831853071795864f * (float)tid * (1.0f/512.0f), &s2, &c2);
        s_tw512[tid] = make_float2(c2, s2);
    }
    if (tid < 8) {
        float s3, c3;
        __sincosf(6.2831853071795864f * (float)tid * (1.0f/64.0f), &s3, &c3);
        s_tw64[tid] = make_float2(c3, s3);
    }
    if (tid < 22) s_maskx[tid] = mxv;

    // ---- stage all 16 frames, mask folded, interleaved complex, swizzled ----
    {
        const float* mp = (const float*)&mk;
        #pragma unroll
        for (int f = 0; f < 4; ++f) {
            float2* SF = &s_slot[(c*4 + f) * CSTRIDE];
            SF[swz(r0      )] = make_float2(((const float*)&vr0)[f] * mp[f],
                                            ((const float*)&vi0)[f] * mp[f]);
            SF[swz(r0 + 256)] = make_float2(((const float*)&vr1)[f] * mp[f],
                                            ((const float*)&vi1)[f] * mp[f]);
        }
        if (tid < 4) {
            #pragma unroll
            for (int f = 0; f < 4; ++f)
                s_slot[(tid*4 + f) * CSTRIDE + 512] =
                    make_float2(((const float*)&nyr)[f] * mp[f],
                                ((const float*)&nyi)[f] * mp[f]);
        }
    }
    if (tid == 0) {
        float acc = 0.f;
        s_ps[0] = 0.f;
        #pragma unroll
        for (int i = 0; i < 22; ++i) { acc += s_maskx[i]; s_ps[i+1] = acc; }
    }
    BAR();   // staging + tables visible

    // ---- FFT: wave wv (0..15) handles frame wv ----
    __builtin_amdgcn_s_setprio(1);
    {
        const int wv = tid >> 6, l = tid & 63;
        fft512i(&s_slot[wv*CSTRIDE], l, s_twzb, s_tw64, s_tw512);
    }
    __builtin_amdgcn_s_setprio(0);
    BAR();   // FFT results visible

    // ---- quad gather + retire: quad p0 = 4*tid ----
    const int P0 = G << 12;   // 4096*G
    float* yout = out + (size_t)b * 524288;
    float* mout = out + 16ull*524288 + (size_t)b * 524288;

    // round 1: p0 in [0, 4096)
    {
        const int p0 = tid << 2;
        if (p0 >= 768) {
            const int F0 = (p0 >> 8) - 3;
            float4 acc = {0.f, 0.f, 0.f, 0.f};
            #pragma unroll
            for (int u = 0; u < 4; ++u) {
                int F = F0 + u;
                int e = (p0 >> 1) - (F << 7);     // even complex index
                float4 v  = *(const float4*)&s_slot[F*CSTRIDE + swz(e)];
                float4 w4 = *(const float4*)&s_wt[p0 - (F << 8)];
                acc.x += v.x * w4.x;  acc.y += v.y * w4.y;
                acc.z += v.z * w4.z;  acc.w += v.w * w4.w;
            }
            float fm = s_ps[(p0 >> 8) + 4] - s_ps[F0 + 3];
            float m = (fm > 0.f) ? 1.0f : 0.0f;
            float4 er = *(const float4*)&s_envr[p0 & 255];
            int s = P0 + p0 - 384;
            float4 r;
            r.x = acc.x * er.x;  r.y = acc.y * er.y;
            r.z = acc.z * er.z;  r.w = acc.w * er.w;
            *(float4*)&yout[s] = r;
            float4 mm = {m, m, m, m};
            *(float4*)&mout[s] = mm;
        } else {
            // left strip quad
            const int thi = p0 >> 8;          // 0..2
            float4 acc = {0.f, 0.f, 0.f, 0.f};
            for (int F = 0; F <= thi; ++F) {
                int e = (p0 >> 1) - (F << 7);
                float4 v  = *(const float4*)&s_slot[F*CSTRIDE + swz(e)];
                float4 w4 = *(const float4*)&s_wt[p0 - (F << 8)];
                acc.x += v.x * w4.x;  acc.y += v.y * w4.y;
                acc.z += v.z * w4.z;  acc.w += v.w * w4.w;
            }
            float fm = s_ps[thi + 4] - s_ps[((p0 - 768) >> 8) + 3];
            float m = (fm > 0.f) ? 1.0f : 0.0f;
            float4 mm = {m, m, m, m};
            if (G == 0) {
                if (p0 >= 384) {
                    float4 e = {0.f, 0.f, 0.f, 0.f};
                    for (int t = 0; t <= thi; ++t) {
                        float4 w4 = *(const float4*)&s_wt[p0 - (t << 8)];
                        e.x += w4.x * w4.x;  e.y += w4.y * w4.y;
                        e.z += w4.z * w4.z;  e.w += w4.w * w4.w;
                    }
                    const float S = 1.0f / 262144.0f;   // e_true = e * 512^2
                    float4 r;
                    r.x = acc.x * S / e.x;  r.y = acc.y * S / e.y;
                    r.z = acc.z * S / e.z;  r.w = acc.w * S / e.w;
                    *(float4*)&yout[p0 - 384] = r;
                    *(float4*)&mout[p0 - 384] = mm;
                }
            } else {
                int s = P0 + p0 - 384;
                if (USE_WS) {
                    *(float4*)&wsL[(size_t)((b << 7) + G) * 768 + p0] = acc;
                } else {
                    atomicAdd(&yout[s+0], acc.x);  atomicAdd(&yout[s+1], acc.y);
                    atomicAdd(&yout[s+2], acc.z);  atomicAdd(&yout[s+3], acc.w);
                }
                *(float4*)&mout[s] = mm;
            }
        }
    }
    // round 2: right strip quad p0 = 4096 + 4*tid (tid < 192)
    if (tid < 192) {
        const int p0 = 4096 + (tid << 2);
        const int Flo = (p0 - 768) >> 8;       // 13..15
        float4 acc = {0.f, 0.f, 0.f, 0.f};
        for (int F = Flo; F < 16; ++F) {
            int e = (p0 >> 1) - (F << 7);
            float4 v  = *(const float4*)&s_slot[F*CSTRIDE + swz(e)];
            float4 w4 = *(const float4*)&s_wt[p0 - (F << 8)];
            acc.x += v.x * w4.x;  acc.y += v.y * w4.y;
            acc.z += v.z * w4.z;  acc.w += v.w * w4.w;
        }
        float fm = s_ps[min(p0 >> 8, 18) + 4] - s_ps[Flo + 3];
        float m = (fm > 0.f) ? 1.0f : 0.0f;
        float4 mm = {m, m, m, m};
        if (G == 127) {
            if (p0 < 4480) {
                float4 e = {0.f, 0.f, 0.f, 0.f};
                for (int t = Flo; t < 16; ++t) {
                    float4 w4 = *(const float4*)&s_wt[p0 - (t << 8)];
                    e.x += w4.x * w4.x;  e.y += w4.y * w4.y;
                    e.z += w4.z * w4.z;  e.w += w4.w * w4.w;
                }
                const float S = 1.0f / 262144.0f;
                int s = P0 + p0 - 384;
                float4 r;
                r.x = acc.x * S / e.x;  r.y = acc.y * S / e.y;
                r.z = acc.z * S / e.z;  r.w = acc.w * S / e.w;
                *(float4*)&yout[s] = r;
                *(float4*)&mout[s] = mm;
            }
        } else {
            int s = P0 + p0 - 384;
            if (USE_WS) {
                *(float4*)&wsR[(size_t)((b << 7) + G) * 768 + (p0 - 4096)] = acc;
            } else {
                atomicAdd(&yout[s+0], acc.x);  atomicAdd(&yout[s+1], acc.y);
                atomicAdd(&yout[s+2], acc.z);  atomicAdd(&yout[s+3], acc.w);
            }
            *(float4*)&mout[s] = mm;
        }
    }
}

// ws path: combine the two strip partials (quad per thread), divide by env.
__global__ void istft_fixup_ws(const float* __restrict__ wsL, const float* __restrict__ wsR,
                               float* __restrict__ out) {
    int idx = blockIdx.x * 256 + threadIdx.x;   // quad index
    if (idx >= 16*127*192) return;
    int q4 = (idx % 192) << 2;        // 0..764
    int t_ = idx / 192;
    int g  = (t_ % 127) + 1;
    int b  = t_ / 127;
    float4 aR = *(const float4*)&wsR[(size_t)((b << 7) + (g-1)) * 768 + q4];
    float4 aL = *(const float4*)&wsL[(size_t)((b << 7) + g) * 768 + q4];
    float4 r;
    #pragma unroll
    for (int cmp = 0; cmp < 4; ++cmp) {
        int j0 = (q4 + cmp) & 255;
        float e = 0.f;
        #pragma unroll
        for (int u = 0; u < 4; ++u) {
            float w = 0.5f - 0.5f * __cosf(6.2831853071795864f * (float)(j0 + (u<<8)) * (1.0f/1024.0f));
            e += w * w;
        }
        float a = ((const float*)&aR)[cmp] + ((const float*)&aL)[cmp];
        ((float*)&r)[cmp] = a / e;
    }
    *(float4*)&out[(size_t)b*524288 + (size_t)((g << 12) + q4 - 384)] = r;
}

// atomic-fallback path
__global__ void istft_zero(float* __restrict__ out) {
    int idx = blockIdx.x * 256 + threadIdx.x;
    if (idx >= 16*127*768) return;
    int q  = idx % 768;
    int t_ = idx / 768;
    int g  = (t_ % 127) + 1;
    int b  = t_ / 127;
    out[(size_t)b*524288 + (g << 12) + q - 384] = 0.f;
}

__global__ void istft_fixup_at(float* __restrict__ out) {
    int idx = blockIdx.x * 256 + threadIdx.x;
    if (idx >= 16*127*768) return;
    int q  = idx % 768;
    int t_ = idx / 768;
    int g  = (t_ % 127) + 1;
    int b  = t_ / 127;
    int j0 = q & 255;
    float e = 0.f;
    #pragma unroll
    for (int u = 0; u < 4; ++u) {
        float w = 0.5f - 0.5f * __cosf(6.2831853071795864f * (float)(j0 + (u<<8)) * (1.0f/1024.0f));
        e += w * w;
    }
    size_t o = (size_t)b*524288 + (size_t)((g << 12) + q - 384);
    out[o] = out[o] / e;
}

extern "C" void kernel_launch(void* const* d_in, const int* in_sizes, int n_in,
                              void* d_out, int out_size, void* d_ws, size_t ws_size,
                              hipStream_t stream) {
    (void)in_sizes; (void)n_in; (void)out_size;
    const float* spec_re = (const float*)d_in[0];
    const float* spec_im = (const float*)d_in[1];
    const float* mask    = (const float*)d_in[2];
    float* out = (float*)d_out;
    const size_t ws_need = 2ull * 16 * 128 * 768 * 4;   // 12.6 MB
    if (ws_size >= ws_need && d_ws != nullptr) {
        float* wsL = (float*)d_ws;
        float* wsR = wsL + 16ull*128*768;
        istft_main<true><<<dim3(128, 16), 1024, 0, stream>>>(spec_re, spec_im, mask, out, wsL, wsR);
        const int nq = 16*127*192;
        istft_fixup_ws<<<(nq + 255)/256, 256, 0, stream>>>(wsL, wsR, out);
    } else {
        const int nstrip = 16*127*768;
        istft_zero<<<(nstrip + 255)/256, 256, 0, stream>>>(out);
        istft_main<false><<<dim3(128, 16), 1024, 0, stream>>>(spec_re, spec_im, mask, out, nullptr, nullptr);
        istft_fixup_at<<<(nstrip + 255)/256, 256, 0, stream>>>(out);
    }
}

// Round 16
// 76.882 us; speedup vs baseline: 2.0420x; 1.0657x over previous
//
#include <hip/hip_runtime.h>

#define THREADS 1024

// raw barrier: wait LDS ops only (NOT vmcnt) so global loads/stores stay in
// flight across the barrier. "memory" clobber pins C++ LDS access order.
#define BAR() do { asm volatile("s_waitcnt lgkmcnt(0)" ::: "memory"); \
                   __builtin_amdgcn_s_barrier();                      \
                   asm volatile("" ::: "memory"); } while (0)

// -------- radix-8 inverse DFT over register index: u[n] = sum_k v[k] e^{+2*pi*i*n*k/8}
__device__ __forceinline__ void dft8(float* vr, float* vi) {
    float t0r=vr[0]+vr[4], t0i=vi[0]+vi[4];
    float t1r=vr[0]-vr[4], t1i=vi[0]-vi[4];
    float t2r=vr[2]+vr[6], t2i=vi[2]+vi[6];
    float t3r=vr[2]-vr[6], t3i=vi[2]-vi[6];
    float t4r=vr[1]+vr[5], t4i=vi[1]+vi[5];
    float t5r=vr[1]-vr[5], t5i=vi[1]-vi[5];
    float t6r=vr[3]+vr[7], t6i=vi[3]+vi[7];
    float t7r=vr[3]-vr[7], t7i=vi[3]-vi[7];
    float e0r=t0r+t2r, e0i=t0i+t2i;
    float e1r=t1r-t3i, e1i=t1i+t3r;   // t1 + i*t3
    float e2r=t0r-t2r, e2i=t0i-t2i;
    float e3r=t1r+t3i, e3i=t1i-t3r;   // t1 - i*t3
    float o0r=t4r+t6r, o0i=t4i+t6i;
    float o1r=t5r-t7i, o1i=t5i+t7r;
    float o2r=t4r-t6r, o2i=t4i-t6i;
    float o3r=t5r+t7i, o3i=t5i-t7r;
    const float C = 0.70710678118654752f;
    float w1r = C*(o1r - o1i), w1i = C*(o1r + o1i);   // W8^1 * o1
    float w2r = -o2i,          w2i = o2r;             // i * o2
    float w3r = -C*(o3r + o3i), w3i = C*(o3r - o3i);  // W8^3 * o3
    vr[0]=e0r+o0r; vi[0]=e0i+o0i;
    vr[1]=e1r+w1r; vi[1]=e1i+w1i;
    vr[2]=e2r+w2r; vi[2]=e2i+w2i;
    vr[3]=e3r+w3r; vi[3]=e3i+w3i;
    vr[4]=e0r-o0r; vi[4]=e0i-o0i;
    vr[5]=e1r-w1r; vi[5]=e1i-w1i;
    vr[6]=e2r-w2r; vi[6]=e2i-w2i;
    vr[7]=e3r-w3r; vi[7]=e3i-w3i;
}

// packed irfft-1024 as 512-pt complex IFFT, in-place in split re/im slot
__device__ __forceinline__ void fft512(float* Re, float* Im, int l,
                                       const float2* s_twzb, const float2* s_tw64,
                                       const float2* s_tw512) {
    const int a_ = l >> 3, b_ = l & 7;
    float zr[8], zi[8];
    float cw = s_twzb[l].x, sw_ = s_twzb[l].y;
    const float C8 = 0.92387953251128675f, S8 = 0.38268343236508977f; // e^{i*pi/8}
    #pragma unroll
    for (int k0 = 0; k0 < 8; ++k0) {
        int k = (k0<<6) + l;
        float xkr = Re[k],     xki = Im[k];
        float xmr = Re[512-k], xmi = Im[512-k];
        if (k == 0) { xki = 0.f; xmi = 0.f; }   // zero Im(X0), Im(X512)
        float Er = 0.5f*(xkr + xmr), Ei = 0.5f*(xki - xmi);
        float Dr = 0.5f*(xkr - xmr), Di = 0.5f*(xki + xmi);
        float Or = cw*Dr - sw_*Di,  Oi = sw_*Dr + cw*Di;
        zr[k0] = Er - Oi;
        zi[k0] = Ei + Or;
        float nc = cw*C8 - sw_*S8; sw_ = sw_*C8 + cw*S8; cw = nc;
    }
    dft8(zr, zi);
    // exchange 1 (XOR-swizzled, <=2-way)
    #pragma unroll
    for (int q = 0; q < 8; ++q) {
        int idx = (q<<6) + l;
        Re[idx ^ (((idx>>6)&7)<<3)] = zr[q];
        Im[idx ^ (((idx>>6)&7)<<3)] = zi[q];
    }
    #pragma unroll
    for (int q = 0; q < 8; ++q) {
        int idx = (a_<<6) + (q<<3) + b_;
        int ph = idx ^ (((idx>>6)&7)<<3);
        zr[q] = Re[ph]; zi[q] = Im[ph];
    }
    { // twiddle2: w64^{n0*k1}, incremental
        float c1 = s_tw64[a_].x, s1 = s_tw64[a_].y;
        float cr = c1, ci = s1;
        #pragma unroll
        for (int q = 1; q < 8; ++q) {
            float tr = zr[q]*cr - zi[q]*ci;
            zi[q] = zr[q]*ci + zi[q]*cr;
            zr[q] = tr;
            float nc = cr*c1 - ci*s1; ci = ci*c1 + cr*s1; cr = nc;
        }
    }
    dft8(zr, zi);
    // exchange 2
    #pragma unroll
    for (int q = 0; q < 8; ++q) {
        int idx = (b_<<6) + (q<<3) + a_;
        int ph = idx ^ (((idx>>6)&7)<<3);
        Re[ph] = zr[q]; Im[ph] = zi[q];
    }
    #pragma unroll
    for (int q = 0; q < 8; ++q) {
        int idx = (q<<6) + l;
        int ph = idx ^ (((idx>>6)&7)<<3);
        zr[q] = Re[ph]; zi[q] = Im[ph];
    }
    { // twiddle3: w512^{(n1*8+n0)*k2}, incremental
        float c1 = s_tw512[l].x, s1 = s_tw512[l].y;
        float cr = c1, ci = s1;
        #pragma unroll
        for (int q = 1; q < 8; ++q) {
            float tr = zr[q]*cr - zi[q]*ci;
            zi[q] = zr[q]*ci + zi[q]*cr;
            zr[q] = tr;
            float nc = cr*c1 - ci*s1; ci = ci*c1 + cr*s1; cr = nc;
        }
    }
    dft8(zr, zi);
    // output: lane l, reg q holds z[64q + l]; x[2n]=Re z[n], x[2n+1]=Im z[n]
    #pragma unroll
    for (int q = 0; q < 8; ++q) {
        Re[(q<<6) + l] = zr[q];
        Im[(q<<6) + l] = zi[q];
    }
}

// one block = (batch b, 16 frames), 16 LDS slots, 1024 threads = 16 waves.
// Quad-based gather: 4 aligned samples/thread -> ds_read_b64 x2 per frame,
// b128 table reads, dwordx4 global stores.
template<bool USE_WS>
__global__ __launch_bounds__(1024, 8) void istft_main(const float* __restrict__ spec_re,
                                                      const float* __restrict__ spec_im,
                                                      const float* __restrict__ mask,
                                                      float* __restrict__ out,
                                                      float* __restrict__ wsL,
                                                      float* __restrict__ wsR)
{
    const int G   = blockIdx.x;   // frame-group 0..127 (frames [16G, 16G+16))
    const int b   = blockIdx.y;   // batch 0..15
    const int tid = threadIdx.x;

    __shared__ __attribute__((aligned(16))) float s_slot[16704]; // 16 slots x 522
    __shared__ __attribute__((aligned(16))) float s_wt[1024];    // hann(j)/512
    __shared__ __attribute__((aligned(16))) float s_envr[256];   // 1/fold(hann^2)
    __shared__ float  s_maskx[22];    // mask frames 16G-3 .. 16G+18 (OOR = 0)
    __shared__ float  s_ps[23];       // prefix sums of s_maskx
    __shared__ float2 s_twzb[64];     // e^{i*pi*l/512}
    __shared__ float2 s_tw64[8];      // e^{2*pi*i*a/64}
    __shared__ float2 s_tw512[64];    // e^{2*pi*i*l/512}

    // ---- issue ALL global loads FIRST (latency hides under table build) ----
    const size_t base = (size_t)b * 513 * 2048 + (size_t)(G * 16);
    const int c  = tid & 3;
    const int r0 = tid >> 2;          // 0..255
    float4 vr0, vi0, vr1, vi1, nyr, nyi;
    float4 mk;
    float mxv = 0.f;
    {
        size_t o0 = base + (size_t)(r0      ) * 2048 + (size_t)(c * 4);
        size_t o1 = base + (size_t)(r0 + 256) * 2048 + (size_t)(c * 4);
        vr0 = *(const float4*)(spec_re + o0);  vi0 = *(const float4*)(spec_im + o0);
        vr1 = *(const float4*)(spec_re + o1);  vi1 = *(const float4*)(spec_im + o1);
        if (tid < 4) {   // Nyquist row 512, chunk tid
            size_t o2 = base + (size_t)512 * 2048 + (size_t)(tid * 4);
            nyr = *(const float4*)(spec_re + o2);
            nyi = *(const float4*)(spec_im + o2);
        }
        mk = *(const float4*)(mask + b*2048 + G*16 + c*4);
        if (tid < 22) {
            int gf = G*16 - 3 + tid;
            mxv = (gf >= 0 && gf < 2048) ? mask[b*2048 + gf] : 0.f;
        }
    }

    // ---- tables (hardware trig; accuracy ~1e-5 << 2e-2 threshold) ----
    {
        float w = 0.5f - 0.5f * __cosf(6.2831853071795864f * (float)tid * (1.0f/1024.0f));
        s_wt[tid] = w * (1.0f/512.0f);
    }
    if (tid < 256) {
        float e = 0.f;
        #pragma unroll
        for (int k = 0; k < 4; ++k) {
            float w = 0.5f - 0.5f * __cosf(6.2831853071795864f * (float)(tid + (k<<8)) * (1.0f/1024.0f));
            e += w * w;
        }
        s_envr[tid] = 1.0f / e;
    }
    if (tid < 64) {
        float s1, c1, s2, c2;
        __sincosf(3.1415926535897932f * (float)tid * (1.0f/512.0f), &s1, &c1);
        s_twzb[tid] = make_float2(c1, s1);
        __sincosf(6.2831853071795864f * (float)tid * (1.0f/512.0f), &s2, &c2);
        s_tw512[tid] = make_float2(c2, s2);
    }
    if (tid < 8) {
        float s3, c3;
        __sincosf(6.2831853071795864f * (float)tid * (1.0f/64.0f), &s3, &c3);
        s_tw64[tid] = make_float2(c3, s3);
    }
    if (tid < 22) s_maskx[tid] = mxv;

    // ---- stage all 16 frames, mask folded ----
    {
        const float* mp = (const float*)&mk;
        #pragma unroll
        for (int f = 0; f < 4; ++f) {
            int fr = (c*4 + f) * 522;
            s_slot[       fr + r0      ] = ((const float*)&vr0)[f] * mp[f];
            s_slot[8352 + fr + r0      ] = ((const float*)&vi0)[f] * mp[f];
            s_slot[       fr + r0 + 256] = ((const float*)&vr1)[f] * mp[f];
            s_slot[8352 + fr + r0 + 256] = ((const float*)&vi1)[f] * mp[f];
        }
        if (tid < 4) {
            #pragma unroll
            for (int f = 0; f < 4; ++f) {
                int fr = (tid*4 + f) * 522;
                s_slot[       fr + 512] = ((const float*)&nyr)[f] * mp[f];
                s_slot[8352 + fr + 512] = ((const float*)&nyi)[f] * mp[f];
            }
        }
    }
    if (tid == 0) {
        float acc = 0.f;
        s_ps[0] = 0.f;
        #pragma unroll
        for (int i = 0; i < 22; ++i) { acc += s_maskx[i]; s_ps[i+1] = acc; }
    }
    BAR();   // staging + tables visible

    // ---- FFT: wave wv (0..15) handles frame wv ----
    __builtin_amdgcn_s_setprio(1);
    {
        const int wv = tid >> 6, l = tid & 63;
        fft512(&s_slot[wv*522], &s_slot[8352 + wv*522], l, s_twzb, s_tw64, s_tw512);
    }
    __builtin_amdgcn_s_setprio(0);
    BAR();   // FFT results visible

    // ---- quad gather + retire ----
    const int P0 = G << 12;   // 4096*G
    float* yout = out + (size_t)b * 524288;
    float* mout = out + 16ull*524288 + (size_t)b * 524288;

    // round 1: quad p0 = 4*tid in [0, 4096)
    {
        const int p0 = tid << 2;
        if (p0 >= 768) {
            // interior: exactly 4 frames, shared window across the quad
            const int F0 = (p0 >> 8) - 3;
            float4 acc = {0.f, 0.f, 0.f, 0.f};
            #pragma unroll
            for (int u = 0; u < 4; ++u) {
                int F = F0 + u;
                int j = p0 - (F << 8);
                float2 re = *(const float2*)&s_slot[       F*522 + (j >> 1)];
                float2 im = *(const float2*)&s_slot[8352 + F*522 + (j >> 1)];
                float4 w4 = *(const float4*)&s_wt[j];
                acc.x += re.x * w4.x;  acc.y += im.x * w4.y;
                acc.z += re.y * w4.z;  acc.w += im.y * w4.w;
            }
            float fm = s_ps[(p0 >> 8) + 4] - s_ps[F0 + 3];
            float m = (fm > 0.f) ? 1.0f : 0.0f;
            float4 er = *(const float4*)&s_envr[p0 & 255];
            int s = P0 + p0 - 384;
            float4 r;
            r.x = acc.x * er.x;  r.y = acc.y * er.y;
            r.z = acc.z * er.z;  r.w = acc.w * er.w;
            *(float4*)&yout[s] = r;
            float4 mm = {m, m, m, m};
            *(float4*)&mout[s] = mm;
        } else {
            // left strip quad
            const int thi = p0 >> 8;          // 0..2
            float4 acc = {0.f, 0.f, 0.f, 0.f};
            for (int F = 0; F <= thi; ++F) {
                int j = p0 - (F << 8);
                float2 re = *(const float2*)&s_slot[       F*522 + (j >> 1)];
                float2 im = *(const float2*)&s_slot[8352 + F*522 + (j >> 1)];
                float4 w4 = *(const float4*)&s_wt[j];
                acc.x += re.x * w4.x;  acc.y += im.x * w4.y;
                acc.z += re.y * w4.z;  acc.w += im.y * w4.w;
            }
            float fm = s_ps[thi + 4] - s_ps[((p0 - 768) >> 8) + 3];
            float m = (fm > 0.f) ? 1.0f : 0.0f;
            float4 mm = {m, m, m, m};
            if (G == 0) {
                if (p0 >= 384) {
                    float4 e = {0.f, 0.f, 0.f, 0.f};
                    for (int t = 0; t <= thi; ++t) {
                        float4 w4 = *(const float4*)&s_wt[p0 - (t << 8)];
                        e.x += w4.x * w4.x;  e.y += w4.y * w4.y;
                        e.z += w4.z * w4.z;  e.w += w4.w * w4.w;
                    }
                    const float S = 1.0f / 262144.0f;   // e_true = e * 512^2
                    float4 r;
                    r.x = acc.x * S / e.x;  r.y = acc.y * S / e.y;
                    r.z = acc.z * S / e.z;  r.w = acc.w * S / e.w;
                    *(float4*)&yout[p0 - 384] = r;
                    *(float4*)&mout[p0 - 384] = mm;
                }
            } else {
                int s = P0 + p0 - 384;
                if (USE_WS) {
                    *(float4*)&wsL[(size_t)((b << 7) + G) * 768 + p0] = acc;
                } else {
                    atomicAdd(&yout[s+0], acc.x);  atomicAdd(&yout[s+1], acc.y);
                    atomicAdd(&yout[s+2], acc.z);  atomicAdd(&yout[s+3], acc.w);
                }
                *(float4*)&mout[s] = mm;
            }
        }
    }
    // round 2: right strip quad p0 = 4096 + 4*tid (tid < 192)
    if (tid < 192) {
        const int p0 = 4096 + (tid << 2);
        const int Flo = (p0 - 768) >> 8;       // 13..15
        float4 acc = {0.f, 0.f, 0.f, 0.f};
        for (int F = Flo; F < 16; ++F) {
            int j = p0 - (F << 8);
            float2 re = *(const float2*)&s_slot[       F*522 + (j >> 1)];
            float2 im = *(const float2*)&s_slot[8352 + F*522 + (j >> 1)];
            float4 w4 = *(const float4*)&s_wt[j];
            acc.x += re.x * w4.x;  acc.y += im.x * w4.y;
            acc.z += re.y * w4.z;  acc.w += im.y * w4.w;
        }
        float fm = s_ps[min(p0 >> 8, 18) + 4] - s_ps[Flo + 3];
        float m = (fm > 0.f) ? 1.0f : 0.0f;
        float4 mm = {m, m, m, m};
        if (G == 127) {
            if (p0 < 4480) {
                float4 e = {0.f, 0.f, 0.f, 0.f};
                for (int t = Flo; t < 16; ++t) {
                    float4 w4 = *(const float4*)&s_wt[p0 - (t << 8)];
                    e.x += w4.x * w4.x;  e.y += w4.y * w4.y;
                    e.z += w4.z * w4.z;  e.w += w4.w * w4.w;
                }
                const float S = 1.0f / 262144.0f;
                int s = P0 + p0 - 384;
                float4 r;
                r.x = acc.x * S / e.x;  r.y = acc.y * S / e.y;
                r.z = acc.z * S / e.z;  r.w = acc.w * S / e.w;
                *(float4*)&yout[s] = r;
                *(float4*)&mout[s] = mm;
            }
        } else {
            int s = P0 + p0 - 384;
            if (USE_WS) {
                *(float4*)&wsR[(size_t)((b << 7) + G) * 768 + (p0 - 4096)] = acc;
            } else {
                atomicAdd(&yout[s+0], acc.x);  atomicAdd(&yout[s+1], acc.y);
                atomicAdd(&yout[s+2], acc.z);  atomicAdd(&yout[s+3], acc.w);
            }
            *(float4*)&mout[s] = mm;
        }
    }
}

// ws path: combine the two strip partials (quad per thread), divide by env.
__global__ void istft_fixup_ws(const float* __restrict__ wsL, const float* __restrict__ wsR,
                               float* __restrict__ out) {
    int idx = blockIdx.x * 256 + threadIdx.x;   // quad index
    if (idx >= 16*127*192) return;
    int q4 = (idx % 192) << 2;        // 0..764
    int t_ = idx / 192;
    int g  = (t_ % 127) + 1;
    int b  = t_ / 127;
    float4 aR = *(const float4*)&wsR[(size_t)((b << 7) + (g-1)) * 768 + q4];
    float4 aL = *(const float4*)&wsL[(size_t)((b << 7) + g) * 768 + q4];
    float4 r;
    #pragma unroll
    for (int cmp = 0; cmp < 4; ++cmp) {
        int j0 = (q4 + cmp) & 255;
        float e = 0.f;
        #pragma unroll
        for (int u = 0; u < 4; ++u) {
            float w = 0.5f - 0.5f * __cosf(6.2831853071795864f * (float)(j0 + (u<<8)) * (1.0f/1024.0f));
            e += w * w;
        }
        float a = ((const float*)&aR)[cmp] + ((const float*)&aL)[cmp];
        ((float*)&r)[cmp] = a / e;
    }
    *(float4*)&out[(size_t)b*524288 + (size_t)((g << 12) + q4 - 384)] = r;
}

// atomic-fallback path
__global__ void istft_zero(float* __restrict__ out) {
    int idx = blockIdx.x * 256 + threadIdx.x;
    if (idx >= 16*127*768) return;
    int q  = idx % 768;
    int t_ = idx / 768;
    int g  = (t_ % 127) + 1;
    int b  = t_ / 127;
    out[(size_t)b*524288 + (g << 12) + q - 384] = 0.f;
}

__global__ void istft_fixup_at(float* __restrict__ out) {
    int idx = blockIdx.x * 256 + threadIdx.x;
    if (idx >= 16*127*768) return;
    int q  = idx % 768;
    int t_ = idx / 768;
    int g  = (t_ % 127) + 1;
    int b  = t_ / 127;
    int j0 = q & 255;
    float e = 0.f;
    #pragma unroll
    for (int u = 0; u < 4; ++u) {
        float w = 0.5f - 0.5f * __cosf(6.2831853071795864f * (float)(j0 + (u<<8)) * (1.0f/1024.0f));
        e += w * w;
    }
    size_t o = (size_t)b*524288 + (size_t)((g << 12) + q - 384);
    out[o] = out[o] / e;
}

extern "C" void kernel_launch(void* const* d_in, const int* in_sizes, int n_in,
                              void* d_out, int out_size, void* d_ws, size_t ws_size,
                              hipStream_t stream) {
    (void)in_sizes; (void)n_in; (void)out_size;
    const float* spec_re = (const float*)d_in[0];
    const float* spec_im = (const float*)d_in[1];
    const float* mask    = (const float*)d_in[2];
    float* out = (float*)d_out;
    const size_t ws_need = 2ull * 16 * 128 * 768 * 4;   // 12.6 MB
    if (ws_size >= ws_need && d_ws != nullptr) {
        float* wsL = (float*)d_ws;
        float* wsR = wsL + 16ull*128*768;
        istft_main<true><<<dim3(128, 16), 1024, 0, stream>>>(spec_re, spec_im, mask, out, wsL, wsR);
        const int nq = 16*127*192;
        istft_fixup_ws<<<(nq + 255)/256, 256, 0, stream>>>(wsL, wsR, out);
    } else {
        const int nstrip = 16*127*768;
        istft_zero<<<(nstrip + 255)/256, 256, 0, stream>>>(out);
        istft_main<false><<<dim3(128, 16), 1024, 0, stream>>>(spec_re, spec_im, mask, out, nullptr, nullptr);
        istft_fixup_at<<<(nstrip + 255)/256, 256, 0, stream>>>(out);
    }
}